// Round 12
// baseline (2194.107 us; speedup 1.0000x reference)
//
#include <hip/hip_runtime.h>
#include <stdint.h>

// Problem constants
#define NBATCH 16
#define NNODE  20
#define TSTEPS 63      // T-1
#define NEDGE  380
#define HID    256
#define RS     280     // hst row stride in shorts (16B-aligned rows, 2-way max on b128)

typedef __bf16 bf16x8 __attribute__((ext_vector_type(8)));
typedef float  f32x4  __attribute__((ext_vector_type(4)));

__device__ __forceinline__ unsigned short f2bf(float f){
  union { float f; unsigned int i; } v; v.f = f;
  return (unsigned short)((v.i + 0x7FFFu + ((v.i >> 16) & 1u)) >> 16);
}
__device__ __forceinline__ bf16x8 as_frag(uint4 v){
  union { uint4 u; bf16x8 b; } c; c.u = v; return c.b;
}
__device__ __forceinline__ float sigmf(float x){ return 1.0f/(1.0f+__expf(-x)); }
__device__ __forceinline__ float tanh_f(float x){ float e=__expf(2.0f*x); return (e-1.0f)/(e+1.0f); }

// In-register 4x4 gate transpose among lanes cl^1, cl^2 (gate-interleaved cols). [proven R4-R11]
__device__ __forceinline__ void xpose4(f32x4& v, int cl){
  float s0 = __shfl_xor((float)v[1], 1), s1 = __shfl_xor((float)v[0], 1);
  float s2 = __shfl_xor((float)v[3], 1), s3 = __shfl_xor((float)v[2], 1);
  bool b0 = (cl & 1);
  float a0 = b0 ? s0 : v[0], a1 = b0 ? v[1] : s1;
  float a2 = b0 ? s2 : v[2], a3 = b0 ? v[3] : s3;
  float t0 = __shfl_xor(a2, 2), t1 = __shfl_xor(a3, 2);
  float t2 = __shfl_xor(a0, 2), t3 = __shfl_xor(a1, 2);
  bool b1 = (cl & 2);
  v[0] = b1 ? t0 : a0; v[1] = b1 ? t1 : a1;
  v[2] = b1 ? a2 : t2; v[3] = b1 ? a3 : t3;
}

// ---------------------------------------------------------------------------
// prep_a: combined weights (fp32) + gate-interleaved biases + zero Afin.
__global__ __launch_bounds__(256) void prep_a(
    const float* __restrict__ We, const float* __restrict__ Wei,
    const float* __restrict__ Wm, const float* __restrict__ Wmi,
    const float* __restrict__ bm, const float* __restrict__ bmi, const float* __restrict__ bmh,
    const float* __restrict__ be, const float* __restrict__ bei, const float* __restrict__ beh,
    float* __restrict__ Wse, float* __restrict__ Wre, float* __restrict__ WcmGI,
    float* __restrict__ bcmGI, float* __restrict__ bceGI, float* __restrict__ Afin){
  int bid = blockIdx.x, tid = threadIdx.x;
  if (bid < 2048){
    int idx = bid*256 + tid;
    int half = idx >> 18;
    int j = idx & 262143;
    int k = j >> 10, nn = j & 1023;
    const float* Wrow = We + (half*256 + k)*128;
    float s = 0.f;
    for (int d = 0; d < 128; ++d) s += Wrow[d] * Wei[d*1024 + nn];
    (half ? Wre : Wse)[k*1024 + nn] = s;
  } else if (bid < 2064){
    int idx = (bid-2048)*256 + tid;
    int d = idx >> 10, ci = idx & 1023;
    int col = (ci & 3)*256 + (ci >> 2);
    float s = 0.f;
    for (int j = 0; j < 128; ++j) s += Wm[d*128 + j] * Wmi[j*1024 + col];
    WcmGI[idx] = s;
  } else if (bid < 2068){
    int ci = (bid-2064)*256 + tid;
    int col = (ci & 3)*256 + (ci >> 2);
    float s = bmi[col] + bmh[col];
    for (int j = 0; j < 128; ++j) s += bm[j] * Wmi[j*1024 + col];
    bcmGI[ci] = s;
  } else if (bid < 2072){
    int ci = (bid-2068)*256 + tid;
    int col = (ci & 3)*256 + (ci >> 2);
    float s = bei[col] + beh[col];
    for (int j = 0; j < 128; ++j) s += be[j] * Wei[j*1024 + col];
    bceGI[ci] = s;
  } else {
    int idx = (bid-2072)*256 + tid;
    if (idx < NBATCH*NEDGE) Afin[idx] = 0.f;
  }
}

// ---------------------------------------------------------------------------
// prep_b packing (verified R2-R11). Tile T (0..63) covers gate-interleaved
// cols ci = T*16 + cl; uint4 index = (T*8 + kt)*64 + lane.
__device__ __forceinline__ void pack_gi(const float* __restrict__ W,
                                        unsigned short* __restrict__ dst, int id){
  int lane = id & 63, kt = (id >> 6) & 7, tt = (id >> 9) & 1, w = (id >> 10) & 7, nb = id >> 13;
  int cl = lane & 15, q = lane >> 4;
  int gcol = (cl & 3)*256 + nb*64 + (w*2 + tt)*4 + (cl >> 2);
  int k0 = kt*32 + q*8;
  unsigned int wb[4];
  #pragma unroll
  for (int p = 0; p < 4; ++p){
    unsigned short a = f2bf(W[(k0+2*p  )*1024 + gcol]);
    unsigned short b = f2bf(W[(k0+2*p+1)*1024 + gcol]);
    wb[p] = (unsigned int)a | ((unsigned int)b << 16);
  }
  ((uint4*)dst)[id] = make_uint4(wb[0], wb[1], wb[2], wb[3]);
}

__device__ __forceinline__ void pack_one(const float* __restrict__ S,
                                         unsigned short* __restrict__ dst, int id, int n){
  int lane = id & 63, kt = (id >> 6) & 7;
  int k0 = kt*32 + ((lane >> 4) << 3);
  unsigned int wb[4];
  #pragma unroll
  for (int p = 0; p < 4; ++p){
    unsigned short a = f2bf(S[(k0+2*p  )*1024 + n]);
    unsigned short b = f2bf(S[(k0+2*p+1)*1024 + n]);
    wb[p] = (unsigned int)a | ((unsigned int)b << 16);
  }
  ((uint4*)dst)[id] = make_uint4(wb[0], wb[1], wb[2], wb[3]);
}

__global__ __launch_bounds__(256) void prep_b(
    const float* __restrict__ Wmh, const float* __restrict__ Weh,
    const float* __restrict__ Wse, const float* __restrict__ Wre,
    unsigned short* __restrict__ pWmh, unsigned short* __restrict__ pWeh,
    unsigned short* __restrict__ pWsr){
  int gid = blockIdx.x*256 + threadIdx.x;
  if (gid < 32768){
    pack_gi(Wmh, pWmh, gid);
  } else if (gid < 65536){
    pack_gi(Weh, pWeh, gid - 32768);
  } else {
    int id = gid - 65536;
    int ng = (id >> 9)*16 + (id & 15);
    const float* S = (ng < 1024) ? Wse : Wre;
    pack_one(S, pWsr, id, ng & 1023);
  }
}

// ---------------------------------------------------------------------------
// motion_lstm: SELF-CONTAINED blocks — no cross-block exchange, no coop launch.
// grid 32 (10 seqs each) x 1024 thr = 16 waves; wave w owns tiles T = w*4..w*4+3
// (full 256 h-cols in-block). Weights register-resident (128 VGPR/lane).
// 1 barrier/step (hst dbuf; update writes nxt while MFMA reads par).
__global__ __launch_bounds__(1024) void motion_lstm(
    const float* __restrict__ X, const float* __restrict__ WcmGI,
    const float* __restrict__ bcmGI, const unsigned short* __restrict__ pWmh,
    unsigned short* __restrict__ hm){
  __shared__ __align__(16) unsigned short hst[2][16*RS];   // 17920 B
  __shared__ float dxs[10*252];                            // 10080 B
  __shared__ __align__(16) float sWc[4*1024];              // 16384 B
  __shared__ __align__(16) float sbc[1024];                // 4096 B
  int tid = threadIdx.x, lane = tid & 63, w = tid >> 6;
  int l15 = lane & 15, quad = lane >> 4;
  int m = blockIdx.x;
  int s0 = m*10;

  uint4 wreg[4][8];
  #pragma unroll
  for (int j = 0; j < 4; ++j)
    #pragma unroll
    for (int kt = 0; kt < 8; ++kt)
      wreg[j][kt] = ((const uint4*)pWmh)[((w*4 + j)*8 + kt)*64 + lane];

  uint4 z4 = make_uint4(0,0,0,0);
  for (int i = tid; i < 2240; i += 1024) ((uint4*)hst)[i] = z4;
  for (int i = tid; i < 4096; i += 1024) sWc[i] = WcmGI[i];
  sbc[tid] = bcmGI[tid];
  for (int i = tid; i < 2520; i += 1024){
    int sl = i / 252; int r = i % 252; int t = r >> 2; int d = r & 3;
    const float* Xp = X + (((size_t)(s0 + sl)*64 + t)*4 + d);
    dxs[i] = Xp[4] - Xp[0];
  }
  __syncthreads();

  float bb[4];
  #pragma unroll
  for (int j = 0; j < 4; ++j) bb[j] = sbc[(w*4 + j)*16 + l15];
  int row = quad*4 + (l15 & 3);
  int hsub = l15 >> 2;
  int slr = row < 10 ? row : 9;
  int seq = s0 + (row < 10 ? row : 9);
  int b2 = seq / 20, nd = seq - (seq/20)*20;
  float ce[4] = {0.f, 0.f, 0.f, 0.f};

  for (int t = 0; t < TSTEPS; ++t){
    int par = t & 1, nxt = par ^ 1;
    f32x4 acc[4];
    #pragma unroll
    for (int j = 0; j < 4; ++j) acc[j] = (f32x4){bb[j], bb[j], bb[j], bb[j]};
    #pragma unroll
    for (int kt = 0; kt < 8; ++kt){
      bf16x8 a = as_frag(*(const uint4*)&hst[par][l15*RS + kt*32 + quad*8]);
      #pragma unroll
      for (int j = 0; j < 4; ++j)
        acc[j] = __builtin_amdgcn_mfma_f32_16x16x32_bf16(a, as_frag(wreg[j][kt]), acc[j], 0, 0, 0);
    }
    // no barrier: update writes hst[nxt], MFMA read hst[par]
    f32x4 dxv = *(const f32x4*)&dxs[slr*252 + t*4];
    #pragma unroll
    for (int j = 0; j < 4; ++j){
      int T = w*4 + j;
      f32x4 v = acc[j];
      xpose4(v, l15);
      #pragma unroll
      for (int d = 0; d < 4; ++d){
        f32x4 wv = *(const f32x4*)&sWc[d*1024 + T*16 + hsub*4];
        v[0] += dxv[d]*wv[0]; v[1] += dxv[d]*wv[1];
        v[2] += dxv[d]*wv[2]; v[3] += dxv[d]*wv[3];
      }
      float iv = sigmf(v[0]), fv = sigmf(v[1]), gg = tanh_f(v[2]), ov = sigmf(v[3]);
      float cc = fv*ce[j] + iv*gg; ce[j] = cc;
      unsigned short hb16 = f2bf(ov*tanh_f(cc));
      hst[nxt][row*RS + T*4 + hsub] = hb16;
      if (row < 10)
        hm[((size_t)(b2*63 + t)*20 + nd)*256 + T*4 + hsub] = hb16;
    }
    __syncthreads();                                  // hst[nxt] visible for t+1
  }
}

// ---------------------------------------------------------------------------
// gsr_gemm: hm (t-major) @ [Wse|Wre] -> gsrT records (40 shorts, 80 B):
//   shorts 0..19 = receiver proj (Wre) nodes 0..19; 20..39 = sender (Wse).
__global__ __launch_bounds__(256) void gsr_gemm(
    const unsigned short* __restrict__ hm, const unsigned short* __restrict__ pWsr,
    unsigned short* __restrict__ gsrT){
  __shared__ __align__(16) unsigned short scol[128*100];   // [col][row], stride 100
  int tid = threadIdx.x, lane = tid & 63, wid = tid >> 6;
  int l15 = lane & 15, quad = lane >> 4;
  int bm = blockIdx.x % 252, bn = blockIdx.x / 252;
  int rowbase = bm*80;
  f32x4 acc[5][2] = {};
  #pragma unroll
  for (int kt = 0; kt < 8; ++kt){
    bf16x8 af[5];
    #pragma unroll
    for (int mt = 0; mt < 5; ++mt)
      af[mt] = as_frag(*(const uint4*)&hm[(size_t)(rowbase + mt*16 + l15)*256 + kt*32 + quad*8]);
    #pragma unroll
    for (int j = 0; j < 2; ++j){
      int ntg = bn*8 + wid*2 + j;
      bf16x8 bfr = as_frag(*(const uint4*)&pWsr[(((size_t)ntg*8 + kt)*64 + lane)*8]);
      #pragma unroll
      for (int mt = 0; mt < 5; ++mt)
        acc[mt][j] = __builtin_amdgcn_mfma_f32_16x16x32_bf16(af[mt], bfr, acc[mt][j], 0, 0, 0);
    }
  }
  #pragma unroll
  for (int mt = 0; mt < 5; ++mt)
    #pragma unroll
    for (int j = 0; j < 2; ++j){
      int colL = (wid*2 + j)*16 + l15;
      unsigned int p0 = (unsigned)f2bf(acc[mt][j][0]) | ((unsigned)f2bf(acc[mt][j][1]) << 16);
      unsigned int p1 = (unsigned)f2bf(acc[mt][j][2]) | ((unsigned)f2bf(acc[mt][j][3]) << 16);
      *(uint2*)&scol[colL*100 + mt*16 + quad*4] = make_uint2(p0, p1);
    }
  __syncthreads();
  int recv = bn >> 3;   // 1 = Wre (slots 0..19), 0 = Wse (slots 20..39)
  #pragma unroll
  for (int rep = 0; rep < 2; ++rep){
    int i = tid + rep*256;
    int btl = i >> 7, colL = i & 127;
    const unsigned short* sp = &scol[colL*100 + btl*20];
    uint2 u0 = *(const uint2*)(sp);
    uint2 u1 = *(const uint2*)(sp+4);
    uint2 u2 = *(const uint2*)(sp+8);
    uint2 u3 = *(const uint2*)(sp+12);
    uint2 u4 = *(const uint2*)(sp+16);
    unsigned short* dp = gsrT + ((size_t)(bm*4 + btl)*1024 + (bn&7)*128 + colL)*40;
    if (recv){
      *(uint4*)(dp)      = make_uint4(u0.x, u0.y, u1.x, u1.y);
      *(uint4*)(dp + 8)  = make_uint4(u2.x, u2.y, u3.x, u3.y);
      *(uint2*)(dp + 16) = u4;
    } else {
      unsigned short* dq = dp + 20;
      *(uint2*)(dq)      = u0;
      *(uint2*)(dq + 4)  = u1;
      *(uint2*)(dq + 8)  = u2;
      *(uint2*)(dq + 12) = u3;
      *(uint2*)(dq + 16) = u4;
    }
  }
}

// ---------------------------------------------------------------------------
// edge_lstm: SELF-CONTAINED blocks — no exchange, no coop launch.
// grid 256 = 16 b x 16 m (24 edges) x 1024 thr = 16 waves; wave w owns tiles
// T = w*4..w*4+3 (full 1024 gate-cols in-block). Weights register-resident.
// gxb[k] per (T, cl): k 0..19 recv node k; k 24..27 sender smin+(k-24); rest 0.
// 2 barriers/step (gxb WAR + hst[nxt] publish).
__global__ __launch_bounds__(1024) void edge_lstm(
    const unsigned short* __restrict__ gsrT, const float* __restrict__ bceGI,
    const unsigned short* __restrict__ pWeh, const float* __restrict__ Wf,
    float* __restrict__ Afin){
  __shared__ __align__(16) unsigned short hst[2][32*RS];   // 35840 B
  __shared__ __align__(16) unsigned short gxb[64*640];     // 81920 B (stride 40 shorts)
  __shared__ __align__(16) float sbce[1024];               // 4096 B
  __shared__ __align__(16) float sWf[256];                 // 1024 B
  int tid = threadIdx.x, lane = tid & 63, w = tid >> 6;
  int l15 = lane & 15, quad = lane >> 4;
  int b = blockIdx.x >> 4, m = blockIdx.x & 15;
  int e0 = m*24;
  int valid = (NEDGE - e0 < 24) ? NEDGE - e0 : 24;
  int smin = e0 / 19;

  uint4 wreg[4][8];
  #pragma unroll
  for (int j = 0; j < 4; ++j)
    #pragma unroll
    for (int kt = 0; kt < 8; ++kt)
      wreg[j][kt] = ((const uint4*)pWeh)[((w*4 + j)*8 + kt)*64 + lane];

  // one-hot A frags: k<20 -> receiver node k; k in [24,28) -> sender smin+(k-24)
  uint4 aoh[2];
  #pragma unroll
  for (int mt = 0; mt < 2; ++mt){
    int row = mt*16 + l15;
    int e = e0 + (row < valid ? row : valid-1);
    int s = e / 19; int rr = e - s*19;
    int sr = s - smin;
    int rc = rr + (rr >= s ? 1 : 0);
    unsigned int wd[4];
    #pragma unroll
    for (int p = 0; p < 4; ++p){
      int k0 = quad*8 + 2*p, k1 = k0 + 1;
      unsigned short a0 = ((k0 < 20) ? (rc == k0) : (k0 >= 24 && k0 < 28 && sr == k0-24)) ? 0x3F80 : 0;
      unsigned short a1 = ((k1 < 20) ? (rc == k1) : (k1 >= 24 && k1 < 28 && sr == k1-24)) ? 0x3F80 : 0;
      wd[p] = (unsigned int)a0 | ((unsigned int)a1 << 16);
    }
    aoh[mt] = make_uint4(wd[0], wd[1], wd[2], wd[3]);
  }

  uint4 z4 = make_uint4(0,0,0,0);
  for (int i = tid; i < 4480; i += 1024) ((uint4*)hst)[i] = z4;
  for (int i = tid; i < 5120; i += 1024) ((uint4*)gxb)[i] = z4;   // zero: unused k-slots MUST be 0-ish (no NaN)
  sbce[tid] = bceGI[tid];
  if (tid < 256) sWf[tid] = Wf[tid];
  __syncthreads();
  {  // stage t=0
    const unsigned short* rec = gsrT + ((size_t)(b*63)*1024 + tid)*40;
    unsigned short* dst = &gxb[(tid >> 4)*640 + (tid & 15)*40];
    *(uint4*)(dst)      = *(const uint4*)(rec);
    *(uint4*)(dst + 8)  = *(const uint4*)(rec + 8);
    *(uint2*)(dst + 16) = *(const uint2*)(rec + 16);
    uint2 sv;
    sv.x = (unsigned)rec[20+smin] | ((unsigned)rec[21+smin] << 16);
    sv.y = (unsigned)rec[22+smin] | ((unsigned)rec[23+smin] << 16);
    *(uint2*)(dst + 24) = sv;
  }
  __syncthreads();

  float bb[4], wfr[4];
  #pragma unroll
  for (int j = 0; j < 4; ++j){
    bb[j]  = sbce[(w*4 + j)*16 + l15];
    wfr[j] = sWf[(w*4 + j)*4 + (l15 >> 2)];
  }
  float ce[2][4]; float epi[2] = {0.f, 0.f};
  #pragma unroll
  for (int mt = 0; mt < 2; ++mt)
    #pragma unroll
    for (int j = 0; j < 4; ++j) ce[mt][j] = 0.f;

  for (int t = 0; t < TSTEPS; ++t){
    int par = t & 1, nxt = par ^ 1;
    // prefetch gsrT(t+1) -> regs (hidden under MFMA)
    uint4 pa, pb; uint2 pc, ps;
    bool pf = (t + 1 < TSTEPS);
    if (pf){
      const unsigned short* rec = gsrT + ((size_t)(b*63 + t + 1)*1024 + tid)*40;
      pa = *(const uint4*)(rec);
      pb = *(const uint4*)(rec + 8);
      pc = *(const uint2*)(rec + 16);
      ps.x = (unsigned)rec[20+smin] | ((unsigned)rec[21+smin] << 16);
      ps.y = (unsigned)rec[22+smin] | ((unsigned)rec[23+smin] << 16);
    }

    f32x4 acc[2][4];
    #pragma unroll
    for (int mt = 0; mt < 2; ++mt)
      #pragma unroll
      for (int j = 0; j < 4; ++j) acc[mt][j] = (f32x4){bb[j], bb[j], bb[j], bb[j]};
    #pragma unroll
    for (int kt = 0; kt < 8; ++kt){
      bf16x8 a0 = as_frag(*(const uint4*)&hst[par][(     l15)*RS + kt*32 + quad*8]);
      bf16x8 a1 = as_frag(*(const uint4*)&hst[par][(16 + l15)*RS + kt*32 + quad*8]);
      #pragma unroll
      for (int j = 0; j < 4; ++j){
        acc[0][j] = __builtin_amdgcn_mfma_f32_16x16x32_bf16(a0, as_frag(wreg[j][kt]), acc[0][j], 0, 0, 0);
        acc[1][j] = __builtin_amdgcn_mfma_f32_16x16x32_bf16(a1, as_frag(wreg[j][kt]), acc[1][j], 0, 0, 0);
      }
    }
    #pragma unroll
    for (int j = 0; j < 4; ++j){
      bf16x8 bx = as_frag(*(const uint4*)&gxb[(w*4 + j)*640 + l15*40 + quad*8]);
      acc[0][j] = __builtin_amdgcn_mfma_f32_16x16x32_bf16(as_frag(aoh[0]), bx, acc[0][j], 0, 0, 0);
      acc[1][j] = __builtin_amdgcn_mfma_f32_16x16x32_bf16(as_frag(aoh[1]), bx, acc[1][j], 0, 0, 0);
    }
    __syncthreads();                                  // gxb(t) consumed
    if (pf){
      unsigned short* dst = &gxb[(tid >> 4)*640 + (tid & 15)*40];
      *(uint4*)(dst)      = pa;
      *(uint4*)(dst + 8)  = pb;
      *(uint2*)(dst + 16) = pc;
      *(uint2*)(dst + 24) = ps;
    }
    #pragma unroll
    for (int j = 0; j < 4; ++j){
      int T = w*4 + j;
      #pragma unroll
      for (int mt = 0; mt < 2; ++mt){
        f32x4 v = acc[mt][j];
        xpose4(v, l15);
        float iv = sigmf(v[0]), fv = sigmf(v[1]), gg = tanh_f(v[2]), ov = sigmf(v[3]);
        float cc = fv*ce[mt][j] + iv*gg; ce[mt][j] = cc;
        float h = ov*tanh_f(cc);
        if (t < 62){
          int row = mt*16 + quad*4 + (l15 & 3);
          hst[nxt][row*RS + T*4 + (l15 >> 2)] = f2bf(h);
        } else {
          epi[mt] += h * wfr[j];
        }
      }
    }
    __syncthreads();                                  // hst[nxt] + gxb(t+1) ready
  }
  // epilogue: reduce over hsub lanes (xor 4, 8), one atomic per (row, wave)
  #pragma unroll
  for (int mt = 0; mt < 2; ++mt){
    float v = epi[mt];
    v += __shfl_xor(v, 4);
    v += __shfl_xor(v, 8);
    if (l15 < 4){
      int row = mt*16 + quad*4 + l15;
      if (row < valid)
        atomicAdd(&Afin[b*380 + e0 + row], v);
    }
  }
}

// ---------------------------------------------------------------------------
// finalize
__global__ __launch_bounds__(256) void finalize(const float* __restrict__ Afin,
                                                const float* __restrict__ bfp,
                                                float* __restrict__ out){
  int idx = blockIdx.x*256 + threadIdx.x;
  if (idx >= 16*400) return;
  int b = idx / 400; int ij = idx % 400; int i = ij / 20; int j = ij % 20;
  float v = 0.f;
  if (i != j){
    int e1 = i*19 + j - (j > i ? 1 : 0);
    int e2 = j*19 + i - (i > j ? 1 : 0);
    float bf = bfp[0];
    v = 0.5f*(sigmf(Afin[b*380 + e1] + bf) + sigmf(Afin[b*380 + e2] + bf));
  }
  out[idx] = v;
}

// ---------------------------------------------------------------------------
extern "C" void kernel_launch(void* const* d_in, const int* in_sizes, int n_in,
                              void* d_out, int out_size, void* d_ws, size_t ws_size,
                              hipStream_t stream){
  (void)in_sizes; (void)n_in; (void)out_size; (void)ws_size;
  const float* X   = (const float*)d_in[0];
  const float* Wm  = (const float*)d_in[3];
  const float* bm  = (const float*)d_in[4];
  const float* Wmi = (const float*)d_in[5];
  const float* bmi = (const float*)d_in[6];
  const float* Wmh = (const float*)d_in[7];
  const float* bmh = (const float*)d_in[8];
  const float* We  = (const float*)d_in[9];
  const float* be  = (const float*)d_in[10];
  const float* Wei = (const float*)d_in[11];
  const float* bei = (const float*)d_in[12];
  const float* Weh = (const float*)d_in[13];
  const float* beh = (const float*)d_in[14];
  const float* Wf  = (const float*)d_in[15];
  const float* bfp = (const float*)d_in[16];

  char* ws = (char*)d_ws;
  float* Wse   = (float*)(ws + 0);                          // 1 MB
  float* Wre   = (float*)(ws + 1048576);                    // 1 MB
  float* WcmGI = (float*)(ws + 2097152);                    // 16 KB
  float* bcmGI = (float*)(ws + 2113536);                    // 4 KB
  float* bceGI = (float*)(ws + 2117632);                    // 4 KB
  unsigned short* pWmh = (unsigned short*)(ws + 2121728);   // 512 KB
  unsigned short* pWeh = (unsigned short*)(ws + 2646016);   // 512 KB
  unsigned short* pWsr = (unsigned short*)(ws + 3170304);   // 1 MB
  unsigned short* hm   = (unsigned short*)(ws + 4218880);   // 10.3 MB (t-major)
  unsigned short* gsrT = (unsigned short*)(ws + 14540800);  // 82.6 MB (40-short recs)
  float* Afin          = (float*)(ws + 97116160);           // 24 KB
  float* out = (float*)d_out;

  hipLaunchKernelGGL(prep_a, dim3(2096), dim3(256), 0, stream,
                     We, Wei, Wm, Wmi, bm, bmi, bmh, be, bei, beh,
                     Wse, Wre, WcmGI, bcmGI, bceGI, Afin);
  hipLaunchKernelGGL(prep_b, dim3(512), dim3(256), 0, stream,
                     Wmh, Weh, Wse, Wre, pWmh, pWeh, pWsr);
  hipLaunchKernelGGL(motion_lstm, dim3(32), dim3(1024), 0, stream,
                     X, WcmGI, bcmGI, pWmh, hm);
  hipLaunchKernelGGL(gsr_gemm, dim3(252*16), dim3(256), 0, stream,
                     hm, pWsr, gsrT);
  hipLaunchKernelGGL(edge_lstm, dim3(256), dim3(1024), 0, stream,
                     gsrT, bceGI, pWeh, Wf, Afin);
  hipLaunchKernelGGL(finalize, dim3(25), dim3(256), 0, stream,
                     Afin, bfp, out);
}

// Round 13
// 1247.579 us; speedup vs baseline: 1.7587x; 1.7587x over previous
//
#include <hip/hip_runtime.h>
#include <stdint.h>

// Problem constants
#define NBATCH 16
#define NNODE  20
#define TSTEPS 63      // T-1
#define NEDGE  380
#define HID    256
#define RS     280     // bf16 hst row stride in shorts (motion)
#define RS8    272     // fp8 hst row stride in bytes (edge)
#define SPIN_MAX (1u << 20)
#define POISON  0xAAAAAAAAAAAAAAAAull

typedef __bf16 bf16x8 __attribute__((ext_vector_type(8)));
typedef float  f32x4  __attribute__((ext_vector_type(4)));

__device__ __forceinline__ unsigned short f2bf(float f){
  union { float f; unsigned int i; } v; v.f = f;
  return (unsigned short)((v.i + 0x7FFFu + ((v.i >> 16) & 1u)) >> 16);
}
__device__ __forceinline__ bf16x8 as_frag(uint4 v){
  union { uint4 u; bf16x8 b; } c; c.u = v; return c.b;
}
__device__ __forceinline__ long as_l(uint2 v){
  union { uint2 u; long l; } c; c.u = v; return c.l;
}
__device__ __forceinline__ float sigmf(float x){ return 1.0f/(1.0f+__expf(-x)); }
__device__ __forceinline__ float tanh_f(float x){ float e=__expf(2.0f*x); return (e-1.0f)/(e+1.0f); }

__device__ __forceinline__ unsigned long long load_ax(const unsigned long long* p){
  return __hip_atomic_load(p, __ATOMIC_RELAXED, __HIP_MEMORY_SCOPE_AGENT);
}
__device__ __forceinline__ void store_ax(unsigned long long* p, unsigned long long v){
  __hip_atomic_store(p, v, __ATOMIC_RELAXED, __HIP_MEMORY_SCOPE_AGENT);
}

// In-register 4x4 gate transpose among lanes cl^1, cl^2. [proven R4-R12]
__device__ __forceinline__ void xpose4(f32x4& v, int cl){
  float s0 = __shfl_xor((float)v[1], 1), s1 = __shfl_xor((float)v[0], 1);
  float s2 = __shfl_xor((float)v[3], 1), s3 = __shfl_xor((float)v[2], 1);
  bool b0 = (cl & 1);
  float a0 = b0 ? s0 : v[0], a1 = b0 ? v[1] : s1;
  float a2 = b0 ? s2 : v[2], a3 = b0 ? v[3] : s3;
  float t0 = __shfl_xor(a2, 2), t1 = __shfl_xor(a3, 2);
  float t2 = __shfl_xor(a0, 2), t3 = __shfl_xor(a1, 2);
  bool b1 = (cl & 2);
  v[0] = b1 ? t0 : a0; v[1] = b1 ? t1 : a1;
  v[2] = b1 ? a2 : t2; v[3] = b1 ? a3 : t3;
}

// ---------------------------------------------------------------------------
// prep_a: combined weights (fp32) + gate-interleaved biases (+ bce scaled x64
// for edge fp8 path) + zero Afin + poison mb3 (motion sentinel exchange).
__global__ __launch_bounds__(256) void prep_a(
    const float* __restrict__ We, const float* __restrict__ Wei,
    const float* __restrict__ Wm, const float* __restrict__ Wmi,
    const float* __restrict__ bm, const float* __restrict__ bmi, const float* __restrict__ bmh,
    const float* __restrict__ be, const float* __restrict__ bei, const float* __restrict__ beh,
    float* __restrict__ Wse, float* __restrict__ Wre, float* __restrict__ WcmGI,
    float* __restrict__ bcmGI, float* __restrict__ bceGI,
    float* __restrict__ Afin, uint4* __restrict__ mb3q){
  int bid = blockIdx.x, tid = threadIdx.x;
  if (bid < 2048){
    int idx = bid*256 + tid;
    int half = idx >> 18;
    int j = idx & 262143;
    int k = j >> 10, nn = j & 1023;
    const float* Wrow = We + (half*256 + k)*128;
    float s = 0.f;
    for (int d = 0; d < 128; ++d) s += Wrow[d] * Wei[d*1024 + nn];
    (half ? Wre : Wse)[k*1024 + nn] = s;
  } else if (bid < 2064){
    int idx = (bid-2048)*256 + tid;
    int d = idx >> 10, ci = idx & 1023;
    int col = (ci & 3)*256 + (ci >> 2);
    float s = 0.f;
    for (int j = 0; j < 128; ++j) s += Wm[d*128 + j] * Wmi[j*1024 + col];
    WcmGI[idx] = s;
  } else if (bid < 2068){
    int ci = (bid-2064)*256 + tid;
    int col = (ci & 3)*256 + (ci >> 2);
    float s = bmi[col] + bmh[col];
    for (int j = 0; j < 128; ++j) s += bm[j] * Wmi[j*1024 + col];
    bcmGI[ci] = s;
  } else if (bid < 2072){
    int ci = (bid-2068)*256 + tid;
    int col = (ci & 3)*256 + (ci >> 2);
    float s = bei[col] + beh[col];
    for (int j = 0; j < 128; ++j) s += be[j] * Wei[j*1024 + col];
    bceGI[ci] = s * 64.0f;                     // x64: edge fp8 product scale
  } else if (bid < 2096){
    int idx = (bid-2072)*256 + tid;
    if (idx < NBATCH*NEDGE) Afin[idx] = 0.f;
  } else {
    int idx = (bid-2096)*256 + tid;            // poison mb3: 49152 uint4
    if (idx < 49152)
      mb3q[idx] = make_uint4(0xAAAAAAAAu,0xAAAAAAAAu,0xAAAAAAAAu,0xAAAAAAAAu);
  }
}

// ---------------------------------------------------------------------------
// prep_b packing: pWmh bf16 (motion), pWeh8 fp8 e4m3 x8-scaled (edge),
// pWsr bf16 (gsr_gemm).
__device__ __forceinline__ void pack_gi(const float* __restrict__ W,
                                        unsigned short* __restrict__ dst, int id){
  int lane = id & 63, kt = (id >> 6) & 7, tt = (id >> 9) & 1, w = (id >> 10) & 7, nb = id >> 13;
  int cl = lane & 15, q = lane >> 4;
  int gcol = (cl & 3)*256 + nb*64 + (w*2 + tt)*4 + (cl >> 2);
  int k0 = kt*32 + q*8;
  unsigned int wb[4];
  #pragma unroll
  for (int p = 0; p < 4; ++p){
    unsigned short a = f2bf(W[(k0+2*p  )*1024 + gcol]);
    unsigned short b = f2bf(W[(k0+2*p+1)*1024 + gcol]);
    wb[p] = (unsigned int)a | ((unsigned int)b << 16);
  }
  ((uint4*)dst)[id] = make_uint4(wb[0], wb[1], wb[2], wb[3]);
}

__device__ __forceinline__ void pack_fp8(const float* __restrict__ W,
                                         unsigned int* __restrict__ dst8, int id){
  int lane = id & 63, kt = (id >> 6) & 7, T = id >> 9;   // T 0..63
  int cl = lane & 15, q = lane >> 4;
  int gcol = (cl & 3)*256 + T*4 + (cl >> 2);
  int k0 = kt*32 + q*8;
  float v[8];
  #pragma unroll
  for (int p = 0; p < 8; ++p) v[p] = W[(size_t)(k0+p)*1024 + gcol] * 8.0f;
  unsigned int b0 = __builtin_amdgcn_cvt_pk_fp8_f32(v[0], v[1], 0, false);
  b0 = __builtin_amdgcn_cvt_pk_fp8_f32(v[2], v[3], b0, true);
  unsigned int b1 = __builtin_amdgcn_cvt_pk_fp8_f32(v[4], v[5], 0, false);
  b1 = __builtin_amdgcn_cvt_pk_fp8_f32(v[6], v[7], b1, true);
  ((uint2*)dst8)[id] = make_uint2(b0, b1);
}

__device__ __forceinline__ void pack_one(const float* __restrict__ S,
                                         unsigned short* __restrict__ dst, int id, int n){
  int lane = id & 63, kt = (id >> 6) & 7;
  int k0 = kt*32 + ((lane >> 4) << 3);
  unsigned int wb[4];
  #pragma unroll
  for (int p = 0; p < 4; ++p){
    unsigned short a = f2bf(S[(k0+2*p  )*1024 + n]);
    unsigned short b = f2bf(S[(k0+2*p+1)*1024 + n]);
    wb[p] = (unsigned int)a | ((unsigned int)b << 16);
  }
  ((uint4*)dst)[id] = make_uint4(wb[0], wb[1], wb[2], wb[3]);
}

__global__ __launch_bounds__(256) void prep_b(
    const float* __restrict__ Wmh, const float* __restrict__ Weh,
    const float* __restrict__ Wse, const float* __restrict__ Wre,
    unsigned short* __restrict__ pWmh, unsigned int* __restrict__ pWeh8,
    unsigned short* __restrict__ pWsr){
  int gid = blockIdx.x*256 + threadIdx.x;
  if (gid < 32768){
    pack_gi(Wmh, pWmh, gid);
  } else if (gid < 65536){
    pack_fp8(Weh, pWeh8, gid - 32768);
  } else {
    int id = gid - 65536;
    int ng = (id >> 9)*16 + (id & 15);
    const float* S = (ng < 1024) ? Wse : Wre;
    pack_one(S, pWsr, id, ng & 1023);
  }
}

// ---------------------------------------------------------------------------
// motion_lstm: R11 proven form (sentinel exchange, grid 128 = 32 m x 4 n, coop).
__global__ __launch_bounds__(512, 2) void motion_lstm(
    const float* __restrict__ X, const float* __restrict__ WcmGI,
    const float* __restrict__ bcmGI, const unsigned short* __restrict__ pWmh,
    unsigned short* __restrict__ hm, unsigned long long* __restrict__ mb3){
  __shared__ __align__(16) unsigned short hst[16*RS];
  __shared__ float dxs[10*252];
  __shared__ __align__(16) float sWc[4*256];
  __shared__ __align__(16) float sbc[256];
  int tid = threadIdx.x, lane = tid & 63, w = tid >> 6;
  int l15 = lane & 15, quad = lane >> 4;
  int m = blockIdx.x & 31, n = blockIdx.x >> 5;
  int s0 = m*10;

  uint4 wreg[2][8];
  #pragma unroll
  for (int tt = 0; tt < 2; ++tt)
    #pragma unroll
    for (int kt = 0; kt < 8; ++kt)
      wreg[tt][kt] = ((const uint4*)pWmh)[(((n*8 + w)*2 + tt)*8 + kt)*64 + lane];

  uint4 z4 = make_uint4(0,0,0,0);
  for (int i = tid; i < 560; i += 512) ((uint4*)hst)[i] = z4;
  for (int i = tid; i < 1024; i += 512) sWc[i] = WcmGI[(i >> 8)*1024 + n*256 + (i & 255)];
  if (tid < 256) sbc[tid] = bcmGI[n*256 + tid];
  for (int i = tid; i < 2520; i += 512){
    int sl = i / 252; int r = i % 252; int t = r >> 2; int d = r & 3;
    const float* Xp = X + (((size_t)(s0 + sl)*64 + t)*4 + d);
    dxs[i] = Xp[4] - Xp[0];
  }
  __syncthreads();

  float bb[2] = { sbc[(w*2+0)*16 + l15], sbc[(w*2+1)*16 + l15] };
  int row = quad*4 + (l15 & 3);
  int hsub = l15 >> 2;
  int slr = row < 10 ? row : 9;
  float ce[2] = {0.f, 0.f};

  for (int t = 0; t < TSTEPS; ++t){
    if (t > 0){
      const unsigned long long* mbp = mb3 + ((size_t)((t-1)%3)*32 + m)*1024;
      unsigned long long pv[2]; int off[2], po[2] = {-1,-1};
      #pragma unroll
      for (int j = 0; j < 2; ++j){
        int i = tid + j*512;
        if (i < 768){
          int which = i >> 8, jj = i & 255;
          int r = jj >> 4, c = jj & 15;
          int np = which + (which >= n ? 1 : 0);
          off[j] = r*64 + np*16 + c;
          po[j]  = r*RS + np*64 + c*4;
          pv[j]  = POISON;
        }
      }
      unsigned int guard = 0; bool need = true;
      while (need){
        need = false;
        #pragma unroll
        for (int j = 0; j < 2; ++j)
          if (po[j] >= 0 && pv[j] == POISON) pv[j] = load_ax(&mbp[off[j]]);
        #pragma unroll
        for (int j = 0; j < 2; ++j)
          if (po[j] >= 0 && pv[j] == POISON) need = true;
        if (need){
          if (++guard > SPIN_MAX) break;
          __builtin_amdgcn_s_sleep(1);
        }
      }
      #pragma unroll
      for (int j = 0; j < 2; ++j)
        if (po[j] >= 0) *(unsigned long long*)&hst[po[j]] = pv[j];
      if (t >= 2 && tid < 256){
        unsigned long long* mbq = mb3 + ((size_t)((t-2)%3)*32 + m)*1024;
        store_ax(&mbq[(size_t)(tid>>4)*64 + n*16 + (tid&15)], POISON);
      }
    }
    __syncthreads();

    f32x4 acc[2];
    acc[0] = (f32x4){bb[0],bb[0],bb[0],bb[0]};
    acc[1] = (f32x4){bb[1],bb[1],bb[1],bb[1]};
    #pragma unroll
    for (int kt = 0; kt < 8; ++kt){
      bf16x8 a = as_frag(*(const uint4*)&hst[l15*RS + kt*32 + quad*8]);
      acc[0] = __builtin_amdgcn_mfma_f32_16x16x32_bf16(a, as_frag(wreg[0][kt]), acc[0], 0, 0, 0);
      acc[1] = __builtin_amdgcn_mfma_f32_16x16x32_bf16(a, as_frag(wreg[1][kt]), acc[1], 0, 0, 0);
    }
    __syncthreads();

    f32x4 dxv = *(const f32x4*)&dxs[slr*252 + t*4];
    #pragma unroll
    for (int tt = 0; tt < 2; ++tt){
      int tl = w*2 + tt;
      f32x4 v = acc[tt];
      xpose4(v, l15);
      #pragma unroll
      for (int d = 0; d < 4; ++d){
        f32x4 wv = *(const f32x4*)&sWc[d*256 + tl*16 + hsub*4];
        v[0] += dxv[d]*wv[0]; v[1] += dxv[d]*wv[1];
        v[2] += dxv[d]*wv[2]; v[3] += dxv[d]*wv[3];
      }
      float iv = sigmf(v[0]), fv = sigmf(v[1]), gg = tanh_f(v[2]), ov = sigmf(v[3]);
      float cc = fv*ce[tt] + iv*gg; ce[tt] = cc;
      hst[row*RS + n*64 + tl*4 + hsub] = f2bf(ov*tanh_f(cc));
    }
    __syncthreads();

    unsigned long long* mbc = mb3 + ((size_t)(t%3)*32 + m)*1024;
    if (tid < 256){
      int r = tid >> 4, c = tid & 15;
      unsigned long long v = *(const unsigned long long*)&hst[r*RS + n*64 + c*4];
      if (t < 62) store_ax(&mbc[(size_t)r*64 + n*16 + c], v);
      if (r < 10){
        int seq = s0 + r;
        int b2 = seq / 20, nd = seq - b2*20;
        *(unsigned long long*)&hm[(((size_t)(b2*63 + t)*20) + nd)*256 + n*64 + c*4] = v;
      }
    }
  }
}

// ---------------------------------------------------------------------------
// gsr_gemm: hm (t-major) @ [Wse|Wre] -> gsrT records (40 shorts, 80 B),
// values PRE-SCALED x64 (edge fp8 product scale).
//   shorts 0..19 = receiver proj (Wre); 20..39 = sender proj (Wse).
__global__ __launch_bounds__(256) void gsr_gemm(
    const unsigned short* __restrict__ hm, const unsigned short* __restrict__ pWsr,
    unsigned short* __restrict__ gsrT){
  __shared__ __align__(16) unsigned short scol[128*100];
  int tid = threadIdx.x, lane = tid & 63, wid = tid >> 6;
  int l15 = lane & 15, quad = lane >> 4;
  int bm = blockIdx.x % 252, bn = blockIdx.x / 252;
  int rowbase = bm*80;
  f32x4 acc[5][2] = {};
  #pragma unroll
  for (int kt = 0; kt < 8; ++kt){
    bf16x8 af[5];
    #pragma unroll
    for (int mt = 0; mt < 5; ++mt)
      af[mt] = as_frag(*(const uint4*)&hm[(size_t)(rowbase + mt*16 + l15)*256 + kt*32 + quad*8]);
    #pragma unroll
    for (int j = 0; j < 2; ++j){
      int ntg = bn*8 + wid*2 + j;
      bf16x8 bfr = as_frag(*(const uint4*)&pWsr[(((size_t)ntg*8 + kt)*64 + lane)*8]);
      #pragma unroll
      for (int mt = 0; mt < 5; ++mt)
        acc[mt][j] = __builtin_amdgcn_mfma_f32_16x16x32_bf16(af[mt], bfr, acc[mt][j], 0, 0, 0);
    }
  }
  #pragma unroll
  for (int mt = 0; mt < 5; ++mt)
    #pragma unroll
    for (int j = 0; j < 2; ++j){
      int colL = (wid*2 + j)*16 + l15;
      unsigned int p0 = (unsigned)f2bf(acc[mt][j][0]*64.f) | ((unsigned)f2bf(acc[mt][j][1]*64.f) << 16);
      unsigned int p1 = (unsigned)f2bf(acc[mt][j][2]*64.f) | ((unsigned)f2bf(acc[mt][j][3]*64.f) << 16);
      *(uint2*)&scol[colL*100 + mt*16 + quad*4] = make_uint2(p0, p1);
    }
  __syncthreads();
  int recv = bn >> 3;
  #pragma unroll
  for (int rep = 0; rep < 2; ++rep){
    int i = tid + rep*256;
    int btl = i >> 7, colL = i & 127;
    const unsigned short* sp = &scol[colL*100 + btl*20];
    uint2 u0 = *(const uint2*)(sp);
    uint2 u1 = *(const uint2*)(sp+4);
    uint2 u2 = *(const uint2*)(sp+8);
    uint2 u3 = *(const uint2*)(sp+12);
    uint2 u4 = *(const uint2*)(sp+16);
    unsigned short* dp = gsrT + ((size_t)(bm*4 + btl)*1024 + (bn&7)*128 + colL)*40;
    if (recv){
      *(uint4*)(dp)      = make_uint4(u0.x, u0.y, u1.x, u1.y);
      *(uint4*)(dp + 8)  = make_uint4(u2.x, u2.y, u3.x, u3.y);
      *(uint2*)(dp + 16) = u4;
    } else {
      unsigned short* dq = dp + 20;
      *(uint2*)(dq)      = u0;
      *(uint2*)(dq + 4)  = u1;
      *(uint2*)(dq + 8)  = u2;
      *(uint2*)(dq + 12) = u3;
      *(uint2*)(dq + 16) = u4;
    }
  }
}

// ---------------------------------------------------------------------------
// edge_lstm: SELF-CONTAINED fp8 blocks. grid 192 = 16 b x 12 m (32 edges).
// 512 thr = 8 waves; wave w owns tiles T = w*8..w*8+7 (full 1024 gate-cols).
// Weights fp8 e4m3 x8 register-resident (128 VGPR); h stored fp8 x8 in LDS.
// Product scale 64: acc = 64*(h.W + xg + bias); v = acc/64.
// xg via bf16 one-hot MFMA (gxb bf16, gsrT pre-scaled x64). 2 barriers/step.
__global__ __launch_bounds__(512) void edge_lstm(
    const unsigned short* __restrict__ gsrT, const float* __restrict__ bceGI,
    const unsigned int* __restrict__ pWeh8, const float* __restrict__ Wf,
    float* __restrict__ Afin){
  __shared__ __align__(16) unsigned char hst8[2][32*RS8];  // 17408 B
  __shared__ __align__(16) unsigned short gxb[64*512];     // 65536 B (T*512 + cl*32 + k)
  __shared__ __align__(16) float sbce[1024];
  __shared__ __align__(16) float sWf[256];
  int tid = threadIdx.x, lane = tid & 63, w = tid >> 6;
  int l15 = lane & 15, quad = lane >> 4;
  int b = blockIdx.x / 12, m = blockIdx.x % 12;
  int e0 = m*32;
  int valid = (NEDGE - e0 < 32) ? NEDGE - e0 : 32;
  int smin = e0 / 19;

  uint2 wreg[8][8];
  #pragma unroll
  for (int j = 0; j < 8; ++j)
    #pragma unroll
    for (int kt = 0; kt < 8; ++kt)
      wreg[j][kt] = ((const uint2*)pWeh8)[((w*8 + j)*8 + kt)*64 + lane];

  // one-hot bf16 A frags for xg K-tile: k<20 recv node k; k in [24,27) sender smin+(k-24)
  uint4 aoh[2];
  #pragma unroll
  for (int mt = 0; mt < 2; ++mt){
    int row = mt*16 + l15;
    int e = e0 + (row < valid ? row : valid-1);
    int s = e / 19; int rr = e - s*19;
    int sr = s - smin;
    int rc = rr + (rr >= s ? 1 : 0);
    unsigned int wd[4];
    #pragma unroll
    for (int p = 0; p < 4; ++p){
      int k0 = quad*8 + 2*p, k1 = k0 + 1;
      unsigned short a0 = ((k0 < 20) ? (rc == k0) : (k0 >= 24 && k0 < 27 && sr == k0-24)) ? 0x3F80 : 0;
      unsigned short a1 = ((k1 < 20) ? (rc == k1) : (k1 >= 24 && k1 < 27 && sr == k1-24)) ? 0x3F80 : 0;
      wd[p] = (unsigned int)a0 | ((unsigned int)a1 << 16);
    }
    aoh[mt] = make_uint4(wd[0], wd[1], wd[2], wd[3]);
  }

  uint4 z4 = make_uint4(0,0,0,0);
  for (int i = tid; i < 1088; i += 512) ((uint4*)hst8)[i] = z4;   // fp8 zero = 0x00
  for (int i = tid; i < 8192; i += 512) ((uint4*)gxb)[i] = z4;
  sbce[tid] = bceGI[tid]; sbce[tid+512] = bceGI[tid+512];
  if (tid < 256) sWf[tid] = Wf[tid];
  __syncthreads();
  #pragma unroll
  for (int r = 0; r < 2; ++r){    // stage t=0 (1024 records, 2/thread)
    int c = tid + r*512;
    const unsigned short* rec = gsrT + ((size_t)(b*63)*1024 + c)*40;
    unsigned short* dst = &gxb[(c >> 4)*512 + (c & 15)*32];
    *(uint4*)(dst)      = *(const uint4*)(rec);
    *(uint4*)(dst + 8)  = *(const uint4*)(rec + 8);
    *(uint2*)(dst + 16) = *(const uint2*)(rec + 16);
    dst[24] = rec[20 + smin]; dst[25] = rec[21 + smin]; dst[26] = rec[22 + smin];
  }
  __syncthreads();

  float bb[8], wfr[8];
  #pragma unroll
  for (int j = 0; j < 8; ++j){
    bb[j]  = sbce[(w*8 + j)*16 + l15];        // pre-scaled x64
    wfr[j] = sWf[(w*8 + j)*4 + (l15 >> 2)];
  }
  float ce[2][8]; float epi[2] = {0.f, 0.f};
  #pragma unroll
  for (int mt = 0; mt < 2; ++mt)
    #pragma unroll
    for (int j = 0; j < 8; ++j) ce[mt][j] = 0.f;

  for (int t = 0; t < TSTEPS; ++t){
    int par = t & 1, nxt = par ^ 1;
    f32x4 acc[2][8];
    #pragma unroll
    for (int mt = 0; mt < 2; ++mt)
      #pragma unroll
      for (int j = 0; j < 8; ++j) acc[mt][j] = (f32x4){bb[j], bb[j], bb[j], bb[j]};
    #pragma unroll
    for (int kt = 0; kt < 8; ++kt){
      long a0 = as_l(*(const uint2*)&hst8[par][(     l15)*RS8 + kt*32 + quad*8]);
      long a1 = as_l(*(const uint2*)&hst8[par][(16 + l15)*RS8 + kt*32 + quad*8]);
      #pragma unroll
      for (int j = 0; j < 8; ++j){
        acc[0][j] = __builtin_amdgcn_mfma_f32_16x16x32_fp8_fp8(a0, as_l(wreg[j][kt]), acc[0][j], 0, 0, 0);
        acc[1][j] = __builtin_amdgcn_mfma_f32_16x16x32_fp8_fp8(a1, as_l(wreg[j][kt]), acc[1][j], 0, 0, 0);
      }
    }
    #pragma unroll
    for (int j = 0; j < 8; ++j){
      bf16x8 bx = as_frag(*(const uint4*)&gxb[(w*8 + j)*512 + l15*32 + quad*8]);
      acc[0][j] = __builtin_amdgcn_mfma_f32_16x16x32_bf16(as_frag(aoh[0]), bx, acc[0][j], 0, 0, 0);
      acc[1][j] = __builtin_amdgcn_mfma_f32_16x16x32_bf16(as_frag(aoh[1]), bx, acc[1][j], 0, 0, 0);
    }
    __syncthreads();                          // gxb(t) + hst[par] consumed
    if (t + 1 < TSTEPS){
      #pragma unroll
      for (int r = 0; r < 2; ++r){
        int c = tid + r*512;
        const unsigned short* rec = gsrT + ((size_t)(b*63 + t + 1)*1024 + c)*40;
        unsigned short* dst = &gxb[(c >> 4)*512 + (c & 15)*32];
        *(uint4*)(dst)      = *(const uint4*)(rec);
        *(uint4*)(dst + 8)  = *(const uint4*)(rec + 8);
        *(uint2*)(dst + 16) = *(const uint2*)(rec + 16);
        dst[24] = rec[20 + smin]; dst[25] = rec[21 + smin]; dst[26] = rec[22 + smin];
      }
    }
    #pragma unroll
    for (int j = 0; j < 8; ++j){
      #pragma unroll
      for (int mt = 0; mt < 2; ++mt){
        f32x4 v = acc[mt][j];
        v[0] *= 0.015625f; v[1] *= 0.015625f; v[2] *= 0.015625f; v[3] *= 0.015625f;
        xpose4(v, l15);
        float iv = sigmf(v[0]), fv = sigmf(v[1]), gg = tanh_f(v[2]), ov = sigmf(v[3]);
        float cc = fv*ce[mt][j] + iv*gg; ce[mt][j] = cc;
        float h = ov*tanh_f(cc);
        if (t < 62){
          unsigned int q = __builtin_amdgcn_cvt_pk_fp8_f32(h*8.0f, h*8.0f, 0, false);
          int row = mt*16 + quad*4 + (l15 & 3);
          hst8[nxt][row*RS8 + (w*8 + j)*4 + (l15 >> 2)] = (unsigned char)q;
        } else {
          epi[mt] += h * wfr[j];
        }
      }
    }
    __syncthreads();                          // hst[nxt] + gxb(t+1) ready
  }
  // epilogue: reduce over hsub lanes (xor 4, 8), one atomic per (row, wave)
  #pragma unroll
  for (int mt = 0; mt < 2; ++mt){
    float v = epi[mt];
    v += __shfl_xor(v, 4);
    v += __shfl_xor(v, 8);
    if (l15 < 4){
      int row = mt*16 + quad*4 + l15;
      if (row < valid)
        atomicAdd(&Afin[b*380 + e0 + row], v);
    }
  }
}

// ---------------------------------------------------------------------------
// finalize
__global__ __launch_bounds__(256) void finalize(const float* __restrict__ Afin,
                                                const float* __restrict__ bfp,
                                                float* __restrict__ out){
  int idx = blockIdx.x*256 + threadIdx.x;
  if (idx >= 16*400) return;
  int b = idx / 400; int ij = idx % 400; int i = ij / 20; int j = ij % 20;
  float v = 0.f;
  if (i != j){
    int e1 = i*19 + j - (j > i ? 1 : 0);
    int e2 = j*19 + i - (i > j ? 1 : 0);
    float bf = bfp[0];
    v = 0.5f*(sigmf(Afin[b*380 + e1] + bf) + sigmf(Afin[b*380 + e2] + bf));
  }
  out[idx] = v;
}

// ---------------------------------------------------------------------------
extern "C" void kernel_launch(void* const* d_in, const int* in_sizes, int n_in,
                              void* d_out, int out_size, void* d_ws, size_t ws_size,
                              hipStream_t stream){
  (void)in_sizes; (void)n_in; (void)out_size; (void)ws_size;
  const float* X   = (const float*)d_in[0];
  const float* Wm  = (const float*)d_in[3];
  const float* bm  = (const float*)d_in[4];
  const float* Wmi = (const float*)d_in[5];
  const float* bmi = (const float*)d_in[6];
  const float* Wmh = (const float*)d_in[7];
  const float* bmh = (const float*)d_in[8];
  const float* We  = (const float*)d_in[9];
  const float* be  = (const float*)d_in[10];
  const float* Wei = (const float*)d_in[11];
  const float* bei = (const float*)d_in[12];
  const float* Weh = (const float*)d_in[13];
  const float* beh = (const float*)d_in[14];
  const float* Wf  = (const float*)d_in[15];
  const float* bfp = (const float*)d_in[16];

  char* ws = (char*)d_ws;
  float* Wse   = (float*)(ws + 0);                          // 1 MB
  float* Wre   = (float*)(ws + 1048576);                    // 1 MB
  float* WcmGI = (float*)(ws + 2097152);                    // 16 KB
  float* bcmGI = (float*)(ws + 2113536);                    // 4 KB
  float* bceGI = (float*)(ws + 2117632);                    // 4 KB (x64 scaled)
  unsigned short* pWmh = (unsigned short*)(ws + 2121728);   // 512 KB
  unsigned int* pWeh8  = (unsigned int*)(ws + 2646016);     // 256 KB (fp8)
  unsigned short* pWsr = (unsigned short*)(ws + 3170304);   // 1 MB
  unsigned short* hm   = (unsigned short*)(ws + 4218880);   // 10.3 MB (t-major)
  unsigned short* gsrT = (unsigned short*)(ws + 14540800);  // 82.6 MB (x64 scaled)
  float* Afin          = (float*)(ws + 97116160);           // 24 KB
  unsigned long long* mb3 = (unsigned long long*)gsrT;      // 786 KB aliased (disjoint lifetime)
  float* out = (float*)d_out;

  hipLaunchKernelGGL(prep_a, dim3(2288), dim3(256), 0, stream,
                     We, Wei, Wm, Wmi, bm, bmi, bmh, be, bei, beh,
                     Wse, Wre, WcmGI, bcmGI, bceGI, Afin, (uint4*)mb3);
  hipLaunchKernelGGL(prep_b, dim3(512), dim3(256), 0, stream,
                     Wmh, Weh, Wse, Wre, pWmh, pWeh8, pWsr);
  {
    void* margs[] = {(void*)&X, (void*)&WcmGI, (void*)&bcmGI, (void*)&pWmh,
                     (void*)&hm, (void*)&mb3};
    hipLaunchCooperativeKernel(reinterpret_cast<void*>(motion_lstm),
                               dim3(128), dim3(512), margs, 0, stream);
  }
  hipLaunchKernelGGL(gsr_gemm, dim3(252*16), dim3(256), 0, stream,
                     hm, pWsr, gsrT);
  hipLaunchKernelGGL(edge_lstm, dim3(192), dim3(512), 0, stream,
                     gsrT, bceGI, pWeh8, Wf, Afin);
  hipLaunchKernelGGL(finalize, dim3(25), dim3(256), 0, stream,
                     Afin, bfp, out);
}